// Round 6
// baseline (7234.707 us; speedup 1.0000x reference)
//
#include <hip/hip_runtime.h>
#include <hip/hip_bf16.h>
#include <cmath>

#define K_NN 20
#define SLOPE 0.2f
#define NSEG 8
#define NSEG_T 4
#define TK 16
#define SCAP 8

// ---------------------------------------------------------------- helpers
__device__ __forceinline__ float lrelu(float x) { return x > 0.f ? x : SLOPE * x; }

// Single-pass sorted-descending top-K insert (branchless select chain).
// Strict > keeps earlier indices on ties (matches jax.lax.top_k lower-index-first).
__device__ __forceinline__ void topk_insert(float (&bd)[K_NN], int (&bi)[K_NN], float nd, int ji) {
  bool c[K_NN];
#pragma unroll
  for (int j = 0; j < K_NN; ++j) c[j] = nd > bd[j];
#pragma unroll
  for (int j = K_NN - 1; j >= 1; --j) {
    bd[j] = c[j] ? (c[j - 1] ? bd[j - 1] : nd) : bd[j];
    bi[j] = c[j] ? (c[j - 1] ? bi[j - 1] : ji) : bi[j];
  }
  bd[0] = c[0] ? nd : bd[0];
  bi[0] = c[0] ? ji : bi[0];
}

// ---------------------------------------------------------------- x0 / coords / masks
__global__ void build_x0_coords(const float* __restrict__ coords, const float* __restrict__ feats,
                                float* __restrict__ x0, float* __restrict__ oC,
                                float* __restrict__ oM, int N) {
  int n = blockIdx.x * 256 + threadIdx.x;
  if (n >= N) return;
  float c0 = coords[n * 3 + 0], c1 = coords[n * 3 + 1], c2 = coords[n * 3 + 2];
  float f = feats[n];
  float4 v = make_float4(c0, c1, c2, f);
  *(float4*)(x0 + (size_t)n * 4) = v;
#pragma unroll
  for (int s = 0; s < 3; ++s) {
    size_t b = (size_t)s * N * 3 + (size_t)n * 3;
    oC[b + 0] = c0; oC[b + 1] = c1; oC[b + 2] = c2;
    oM[(size_t)s * N + n] = 0.f;
  }
}

// ---------------------------------------------------------------- squared norms
__global__ void compute_xx(const float* __restrict__ x, int ld, int C,
                           float* __restrict__ xx, int N) {
  int n = blockIdx.x * 256 + threadIdx.x;
  if (n >= N) return;
  const float* r = x + (size_t)n * ld;
  float s = 0.f;
  for (int c = 0; c < C; c += 4) {
    float4 v = *(const float4*)(r + c);
    s += v.x * v.x; s += v.y * v.y; s += v.z * v.z; s += v.w * v.w;
  }
  xx[n] = s;
}

// ---------------------------------------------------------------- small-C fused kNN (layer 1 only)
template <int C>
__global__ __launch_bounds__(256, 2) void knn_seg(
    const float* __restrict__ xP, int ld, const float* __restrict__ xx,
    float* __restrict__ pd, int* __restrict__ pi, int N, int segLen) {
  constexpr int T = 64;
  __shared__ float tile[T * C];
  __shared__ float txx[T];
  __shared__ float sd_st[SCAP * 256];
  __shared__ int si_st[SCAP * 256];
  int tid = threadIdx.x;
  int q = blockIdx.x * 256 + tid;
  int j0 = blockIdx.y * segLen;

  float4 qv[C / 4];
#pragma unroll
  for (int c4 = 0; c4 < C / 4; ++c4) qv[c4] = *(const float4*)(xP + (size_t)q * ld + c4 * 4);
  float xxq = xx[q];

  float bd[K_NN]; int bi[K_NN];
#pragma unroll
  for (int k = 0; k < K_NN; ++k) { bd[k] = -INFINITY; bi[k] = 0; }
  float thr = -INFINITY;
  int cnt = 0;

  for (int jt = j0; jt < j0 + segLen; jt += T) {
    constexpr int TOT4 = T * C / 4;
    for (int f = tid; f < TOT4; f += 256) {
      int t = f / (C / 4), c4 = f % (C / 4);
      *(float4*)(tile + t * C + c4 * 4) = *(const float4*)(xP + (size_t)(jt + t) * ld + c4 * 4);
    }
    if (tid < T) txx[tid] = xx[jt + tid];
    __syncthreads();
#pragma unroll 2
    for (int t = 0; t < T; ++t) {
      const float4* rp = (const float4*)(tile + t * C);
      float dot = 0.f;
#pragma unroll
      for (int c4 = 0; c4 < C / 4; ++c4) {
        float4 v = rp[c4];
        dot += qv[c4].x * v.x; dot += qv[c4].y * v.y;
        dot += qv[c4].z * v.z; dot += qv[c4].w * v.w;
      }
      float nd = 2.f * dot - xxq - txx[t];
      if (nd > thr) {
        sd_st[cnt * 256 + tid] = nd;
        si_st[cnt * 256 + tid] = jt + t;
        cnt++;
      }
      if (__any(cnt == SCAP)) {
        for (int e = 0; e < cnt; ++e) {
          float dnd = sd_st[e * 256 + tid];
          int dji = si_st[e * 256 + tid];
          if (dnd > bd[K_NN - 1]) topk_insert(bd, bi, dnd, dji);
        }
        cnt = 0;
        thr = bd[K_NN - 1];
      }
    }
    __syncthreads();
  }
  for (int e = 0; e < cnt; ++e) {
    float dnd = sd_st[e * 256 + tid];
    int dji = si_st[e * 256 + tid];
    if (dnd > bd[K_NN - 1]) topk_insert(bd, bi, dnd, dji);
  }

  size_t base = ((size_t)blockIdx.y * N + q) * K_NN;
#pragma unroll
  for (int k = 0; k < K_NN; ++k) { pd[base + k] = bd[k]; pi[base + k] = bi[k]; }
}

// ---------------------------------------------------------------- register-tiled kNN (C = 64 / 128)
// Block = 64 queries; 16x16 threads each own a 4x4 distance sub-tile of a
// 64x64 pair tile -> 8 ds_read_b128 feed 64 FMA (vs 1:4 before). Q/C tiles
// XOR-swizzled (slot = kc ^ ((row>>2)&15)) to kill column-of-rows bank
// stacking. Distances go through a stride-65 LDS tile ((lane+j)%32 -> 2-way,
// free) to wave 0, which owns per-query top-k with the deferred-stack insert.
template <int C>
__global__ __launch_bounds__(256) void knn_tile(
    const float* __restrict__ xP, int ld, const float* __restrict__ xx,
    float* __restrict__ pd, int* __restrict__ pi, int N, int segLen) {
  constexpr int SQ4 = (C + 4) / 4;  // float4 stride of LDS tile rows
  __shared__ float4 Qs[64 * SQ4];
  __shared__ float4 Cs[64 * SQ4];
  __shared__ float dist[64 * 65];
  __shared__ float qxx[64];
  __shared__ float txx[64];
  __shared__ float sd_st[SCAP * 64];
  __shared__ int si_st[SCAP * 64];

  int tid = threadIdx.x;
  int tx = tid & 15, ty = tid >> 4;
  int q0 = blockIdx.x * 64;
  int j0 = blockIdx.y * segLen;

  // stage Q tile (swizzled) + qxx, once per block
  for (int p = tid; p < 64 * (C / 4); p += 256) {
    int r = p / (C / 4), c4 = p % (C / 4);
    Qs[r * SQ4 + (c4 ^ ((r >> 2) & 15))] =
        *(const float4*)(xP + (size_t)(q0 + r) * ld + c4 * 4);
  }
  if (tid < 64) qxx[tid] = xx[q0 + tid];

  float bd[K_NN]; int bi[K_NN];
#pragma unroll
  for (int k = 0; k < K_NN; ++k) { bd[k] = -INFINITY; bi[k] = 0; }
  float thr = -INFINITY;
  int cnt = 0;

  for (int jt = j0; jt < j0 + segLen; jt += 64) {
    // stage candidate tile (swizzled) + txx
    for (int p = tid; p < 64 * (C / 4); p += 256) {
      int r = p / (C / 4), c4 = p % (C / 4);
      Cs[r * SQ4 + (c4 ^ ((r >> 2) & 15))] =
          *(const float4*)(xP + (size_t)(jt + r) * ld + c4 * 4);
    }
    if (tid < 64) txx[tid] = xx[jt + tid];
    __syncthreads();  // A: tiles ready; also orders prev scan before dist overwrite

    float acc[4][4] = {};
    for (int kc = 0; kc < C / 4; ++kc) {
      float4 qa[4], ca[4];
#pragma unroll
      for (int i = 0; i < 4; ++i) qa[i] = Qs[(ty * 4 + i) * SQ4 + (kc ^ ty)];
#pragma unroll
      for (int j = 0; j < 4; ++j) ca[j] = Cs[(tx * 4 + j) * SQ4 + (kc ^ tx)];
#pragma unroll
      for (int i = 0; i < 4; ++i)
#pragma unroll
        for (int j = 0; j < 4; ++j) {
          acc[i][j] += qa[i].x * ca[j].x;
          acc[i][j] += qa[i].y * ca[j].y;
          acc[i][j] += qa[i].z * ca[j].z;
          acc[i][j] += qa[i].w * ca[j].w;
        }
    }
    // epilogue: full neg-distance into dist tile
#pragma unroll
    for (int i = 0; i < 4; ++i) {
      float xq = qxx[ty * 4 + i];
#pragma unroll
      for (int j = 0; j < 4; ++j)
        dist[(ty * 4 + i) * 65 + tx * 4 + j] =
            2.f * acc[i][j] - xq - txx[tx * 4 + j];
    }
    __syncthreads();  // B: dist ready

    if (tid < 64) {  // wave 0: scan 64 candidates for its query
      for (int j = 0; j < 64; ++j) {
        float nd = dist[tid * 65 + j];
        if (nd > thr) {
          sd_st[cnt * 64 + tid] = nd;
          si_st[cnt * 64 + tid] = jt + j;
          cnt++;
        }
        if (__any(cnt == SCAP)) {
          for (int e = 0; e < cnt; ++e) {
            float dnd = sd_st[e * 64 + tid];
            int dji = si_st[e * 64 + tid];
            if (dnd > bd[K_NN - 1]) topk_insert(bd, bi, dnd, dji);
          }
          cnt = 0;
          thr = bd[K_NN - 1];
        }
      }
    }
    // no barrier: next iter's barrier A orders scan vs next dist write
  }

  if (tid < 64) {
    for (int e = 0; e < cnt; ++e) {
      float dnd = sd_st[e * 64 + tid];
      int dji = si_st[e * 64 + tid];
      if (dnd > bd[K_NN - 1]) topk_insert(bd, bi, dnd, dji);
    }
    size_t base = ((size_t)blockIdx.y * N + q0 + tid) * K_NN;
#pragma unroll
    for (int k = 0; k < K_NN; ++k) { pd[base + k] = bd[k]; pi[base + k] = bi[k]; }
  }
}

// ---------------------------------------------------------------- merge per-segment top-k lists
__global__ void knn_merge(const float* __restrict__ pd, const int* __restrict__ pi,
                          int* __restrict__ idx, int N, int S) {
  int q = blockIdx.x * 256 + threadIdx.x;
  if (q >= N) return;
  float bd[K_NN]; int bi[K_NN];
#pragma unroll
  for (int k = 0; k < K_NN; ++k) { bd[k] = -INFINITY; bi[k] = 0; }
  for (int s = 0; s < S; ++s) {
    size_t base = ((size_t)s * N + q) * K_NN;
    for (int k = 0; k < K_NN; ++k) {
      float nd = pd[base + k];
      if (!(nd > bd[K_NN - 1])) break;  // lists sorted descending
      topk_insert(bd, bi, nd, pi[base + k]);
    }
  }
#pragma unroll
  for (int k = 0; k < K_NN; ++k) idx[(size_t)q * K_NN + k] = bi[k];
}

// ---------------------------------------------------------------- weight prep: wcat = [w_A ; w_B - w_A]
__global__ void prep_wcat(const float* __restrict__ w, float* __restrict__ wcat, int O, int C) {
  int i = blockIdx.x * 256 + threadIdx.x;
  if (i >= O * C) return;
  int o = i / C, c = i % C;
  float wa = w[(size_t)o * 2 * C + c];
  float wb = w[(size_t)o * 2 * C + C + c];
  wcat[(size_t)o * C + c] = wa;
  wcat[((size_t)O + o) * C + c] = wb - wa;
}

// ---------------------------------------------------------------- tiled SGEMM-NT: Out[m][n] = ep(sum_k A[m][k]*B[n][k])
// MODE 0: plain   MODE 1: lrelu(acc*s[n]+c[n])   MODE 2: acc*s[n]+c[n]
template <int MODE>
__global__ __launch_bounds__(256) void gemm_nt(
    const float* __restrict__ A, int lda, const float* __restrict__ B, int ldb,
    float* __restrict__ Out, int ldo, int M, int Nout, int Kdim,
    const float* __restrict__ sv, const float* __restrict__ cv) {
  __shared__ float As[TK][64];
  __shared__ float Bs[TK][64];
  int tid = threadIdx.x;
  int tx = tid & 15, ty = tid >> 4;
  int m0 = blockIdx.x * 64, n0 = blockIdx.y * 64;
  int lrow = tid >> 2, lkq = tid & 3;
  float acc[4][4] = {};

  for (int k0 = 0; k0 < Kdim; k0 += TK) {
    float4 av = make_float4(0.f, 0.f, 0.f, 0.f), bv = make_float4(0.f, 0.f, 0.f, 0.f);
    if (k0 + lkq * 4 < Kdim) {
      av = *(const float4*)(A + (size_t)(m0 + lrow) * lda + k0 + lkq * 4);
      bv = *(const float4*)(B + (size_t)(n0 + lrow) * ldb + k0 + lkq * 4);
    }
    As[lkq * 4 + 0][lrow] = av.x; As[lkq * 4 + 1][lrow] = av.y;
    As[lkq * 4 + 2][lrow] = av.z; As[lkq * 4 + 3][lrow] = av.w;
    Bs[lkq * 4 + 0][lrow] = bv.x; Bs[lkq * 4 + 1][lrow] = bv.y;
    Bs[lkq * 4 + 2][lrow] = bv.z; Bs[lkq * 4 + 3][lrow] = bv.w;
    __syncthreads();
#pragma unroll
    for (int kk = 0; kk < TK; ++kk) {
      float a[4], b[4];
      *(float4*)a = *(const float4*)&As[kk][ty * 4];
      *(float4*)b = *(const float4*)&Bs[kk][tx * 4];
#pragma unroll
      for (int i = 0; i < 4; ++i)
#pragma unroll
        for (int j = 0; j < 4; ++j) acc[i][j] += a[i] * b[j];
    }
    __syncthreads();
  }

  float4 s4 = make_float4(1.f, 1.f, 1.f, 1.f), c4 = make_float4(0.f, 0.f, 0.f, 0.f);
  if (MODE != 0) {
    s4 = *(const float4*)(sv + n0 + tx * 4);
    c4 = *(const float4*)(cv + n0 + tx * 4);
  }
#pragma unroll
  for (int i = 0; i < 4; ++i) {
    float4 r = make_float4(acc[i][0], acc[i][1], acc[i][2], acc[i][3]);
    if (MODE != 0) {
      r.x = r.x * s4.x + c4.x; r.y = r.y * s4.y + c4.y;
      r.z = r.z * s4.z + c4.z; r.w = r.w * s4.w + c4.w;
    }
    if (MODE == 1) { r.x = lrelu(r.x); r.y = lrelu(r.y); r.z = lrelu(r.z); r.w = lrelu(r.w); }
    *(float4*)(Out + (size_t)(m0 + ty * 4 + i) * ldo + n0 + tx * 4) = r;
  }
}

// ---------------------------------------------------------------- gather-max epilogue of EdgeConv
template <int O>
__global__ void edge_max(const float* __restrict__ U, const int* __restrict__ idx,
                         const float* __restrict__ sv, const float* __restrict__ cv,
                         float* __restrict__ out, int N) {
  constexpr int TPP = O / 4;
  constexpr int PPB = 256 / TPP;
  int tid = threadIdx.x;
  int n = blockIdx.x * PPB + tid / TPP;
  int o4 = tid % TPP;
  const int* ir = idx + (size_t)n * K_NN;
  float4 m = make_float4(-INFINITY, -INFINITY, -INFINITY, -INFINITY);
#pragma unroll
  for (int k = 0; k < K_NN; ++k) {
    int j = ir[k];
    float4 t = *(const float4*)(U + (size_t)j * (2 * O) + o4 * 4);
    m.x = fmaxf(m.x, t.x); m.y = fmaxf(m.y, t.y);
    m.z = fmaxf(m.z, t.z); m.w = fmaxf(m.w, t.w);
  }
  float4 v = *(const float4*)(U + (size_t)n * (2 * O) + O + o4 * 4);
  float4 s4 = *(const float4*)(sv + o4 * 4);
  float4 c4 = *(const float4*)(cv + o4 * 4);
  float4 r;
  r.x = lrelu(s4.x * (v.x + m.x) + c4.x);
  r.y = lrelu(s4.y * (v.y + m.y) + c4.y);
  r.z = lrelu(s4.z * (v.z + m.z) + c4.z);
  r.w = lrelu(s4.w * (v.w + m.w) + c4.w);
  *(float4*)(out + (size_t)n * 512 + o4 * 4) = r;
}

// ---------------------------------------------------------------- transpose (N,768) -> (768,N)
__global__ void transpose_nt(const float* __restrict__ in, float* __restrict__ out, int N, int Cc) {
  __shared__ float t[32][33];
  int bx = blockIdx.x, by = blockIdx.y;
  int lx = threadIdx.x, ly = threadIdx.y;
#pragma unroll
  for (int i = 0; i < 4; ++i)
    t[ly + i * 8][lx] = in[(size_t)(by * 32 + ly + i * 8) * Cc + bx * 32 + lx];
  __syncthreads();
#pragma unroll
  for (int i = 0; i < 4; ++i)
    out[(size_t)(bx * 32 + ly + i * 8) * N + by * 32 + lx] = t[lx][ly + i * 8];
}

// ---------------------------------------------------------------- sem logits: (N,256) @ (20,256)^T + b
__global__ void sem_kernel(const float* __restrict__ T1, const float* __restrict__ wsem,
                           const float* __restrict__ bsem, float* __restrict__ out, int N) {
  int tid = threadIdx.x;
  int n = blockIdx.x * 8 + (tid >> 5);
  int g = tid & 31;
  if (g < 20) {
    const float* row = T1 + (size_t)n * 768 + 512;
    const float* wr = wsem + (size_t)g * 256;
    float acc = 0.f;
    for (int o = 0; o < 256; ++o) acc += row[o] * wr[o];
    out[(size_t)n * 20 + g] = acc + bsem[g];
  }
}

// ---------------------------------------------------------------- per-layer drivers
template <int C, int O>
static void run_layer_seg(const float* x, int ld, const float* wc, const float* sv,
                          const float* cv, float* outcol, float* xxb, int* idxb, float* pd,
                          int* pi, float* U, int N, hipStream_t stream) {
  compute_xx<<<N / 256, 256, 0, stream>>>(x, ld, C, xxb, N);
  knn_seg<C><<<dim3(N / 256, NSEG), 256, 0, stream>>>(x, ld, xxb, pd, pi, N, N / NSEG);
  knn_merge<<<N / 256, 256, 0, stream>>>(pd, pi, idxb, N, NSEG);
  gemm_nt<0><<<dim3(N / 64, (2 * O) / 64), 256, 0, stream>>>(x, ld, wc, C, U, 2 * O, N, 2 * O, C,
                                                             nullptr, nullptr);
  edge_max<O><<<N / (256 / (O / 4)), 256, 0, stream>>>(U, idxb, sv, cv, outcol, N);
}

template <int C, int O>
static void run_layer_tile(const float* x, int ld, const float* wc, const float* sv,
                           const float* cv, float* outcol, float* xxb, int* idxb, float* pd,
                           int* pi, float* U, int N, hipStream_t stream) {
  compute_xx<<<N / 256, 256, 0, stream>>>(x, ld, C, xxb, N);
  knn_tile<C><<<dim3(N / 64, NSEG_T), 256, 0, stream>>>(x, ld, xxb, pd, pi, N, N / NSEG_T);
  knn_merge<<<N / 256, 256, 0, stream>>>(pd, pi, idxb, N, NSEG_T);
  gemm_nt<0><<<dim3(N / 64, (2 * O) / 64), 256, 0, stream>>>(x, ld, wc, C, U, 2 * O, N, 2 * O, C,
                                                             nullptr, nullptr);
  edge_max<O><<<N / (256 / (O / 4)), 256, 0, stream>>>(U, idxb, sv, cv, outcol, N);
}

extern "C" void kernel_launch(void* const* d_in, const int* in_sizes, int n_in,
                              void* d_out, int out_size, void* d_ws, size_t ws_size,
                              hipStream_t stream) {
  const int N = in_sizes[0] / 3;  // 16384
  const float* coords = (const float*)d_in[0];
  const float* feats  = (const float*)d_in[1];
  const float* w1 = (const float*)d_in[2];
  const float* s1 = (const float*)d_in[3];
  const float* c1 = (const float*)d_in[4];
  const float* w2 = (const float*)d_in[5];
  const float* s2 = (const float*)d_in[6];
  const float* c2 = (const float*)d_in[7];
  const float* w3 = (const float*)d_in[8];
  const float* s3 = (const float*)d_in[9];
  const float* c3 = (const float*)d_in[10];
  const float* w4 = (const float*)d_in[11];
  const float* s4 = (const float*)d_in[12];
  const float* c4 = (const float*)d_in[13];
  const float* w5 = (const float*)d_in[14];
  const float* s5 = (const float*)d_in[15];
  const float* c5 = (const float*)d_in[16];
  const float* wf = (const float*)d_in[17];
  const float* sf = (const float*)d_in[18];
  const float* cf = (const float*)d_in[19];
  const float* wsem = (const float*)d_in[20];
  const float* bsem = (const float*)d_in[21];

  // workspace layout (floats). pd/pi alias the (not-yet-live) T1 buffer.
  float* base = (float*)d_ws;
  size_t off = 0;
  float* XC  = base + off; off += (size_t)N * 512;   // [x1|x2|x3|x4] point-major, stride 512
  float* UX5 = base + off; off += (size_t)N * 512;   // u|v tables per layer, later x5
  float* x0  = base + off; off += (size_t)N * 4;
  float* xxb = base + off; off += (size_t)N;
  int*   idxb = (int*)(base + off); off += (size_t)N * K_NN;
  float* wc1 = base + off; off += 128 * 4;
  float* wc2 = base + off; off += 128 * 64;
  float* wc3 = base + off; off += 256 * 64;
  float* wc4 = base + off; off += 512 * 128;
  float* T1  = base + off; off += (size_t)N * 768;
  float* pd = T1;
  int*   pi = (int*)(T1 + (size_t)NSEG * N * K_NN);

  float* oF = (float*)d_out;                       // ms_feats (3,256,N)
  float* oC = oF + (size_t)3 * 256 * N;            // ms_coords (3,N,3)
  float* oM = oC + (size_t)3 * N * 3;              // ms_masks (3,N)
  float* oL = oM + (size_t)3 * N;                  // sem_logits (1,N,20)

  build_x0_coords<<<N / 256, 256, 0, stream>>>(coords, feats, x0, oC, oM, N);

  prep_wcat<<<(64 * 4 + 255) / 256, 256, 0, stream>>>(w1, wc1, 64, 4);
  prep_wcat<<<(64 * 64 + 255) / 256, 256, 0, stream>>>(w2, wc2, 64, 64);
  prep_wcat<<<(128 * 64 + 255) / 256, 256, 0, stream>>>(w3, wc3, 128, 64);
  prep_wcat<<<(256 * 128 + 255) / 256, 256, 0, stream>>>(w4, wc4, 256, 128);

  run_layer_seg<4, 64>(x0, 4, wc1, s1, c1, XC + 0, xxb, idxb, pd, pi, UX5, N, stream);
  run_layer_tile<64, 64>(XC + 0, 512, wc2, s2, c2, XC + 64, xxb, idxb, pd, pi, UX5, N, stream);
  run_layer_tile<64, 128>(XC + 64, 512, wc3, s3, c3, XC + 128, xxb, idxb, pd, pi, UX5, N, stream);
  run_layer_tile<128, 256>(XC + 128, 512, wc4, s4, c4, XC + 256, xxb, idxb, pd, pi, UX5, N, stream);

  // x5 = lrelu(w5 @ cat * s5 + c5)  -> UX5 (N,512)
  gemm_nt<1><<<dim3(N / 64, 8), 256, 0, stream>>>(XC, 512, w5, 512, UX5, 512, N, 512, 512, s5, c5);
  // T1 = x5 @ wf^T * sf + cf  (wf viewed as (768,512))  -> (N,768)
  gemm_nt<2><<<dim3(N / 64, 12), 256, 0, stream>>>(UX5, 512, wf, 512, T1, 768, N, 768, 512, sf, cf);
  // ms_feats = T1^T
  transpose_nt<<<dim3(24, N / 32), dim3(32, 8), 0, stream>>>(T1, oF, N, 768);
  // sem_logits from T1 cols [512,768)
  sem_kernel<<<N / 8, 256, 0, stream>>>(T1, wsem, bsem, oL, N);
}

// Round 7
// 4064.622 us; speedup vs baseline: 1.7799x; 1.7799x over previous
//
#include <hip/hip_runtime.h>
#include <hip/hip_bf16.h>
#include <cmath>

#define K_NN 20
#define SLOPE 0.2f
#define NSEG 8
#define TK 16
#define SCAP 8

typedef _Float16 h8 __attribute__((ext_vector_type(8)));
typedef _Float16 h4 __attribute__((ext_vector_type(4)));
typedef float f4v __attribute__((ext_vector_type(4)));

// ---------------------------------------------------------------- helpers
__device__ __forceinline__ float lrelu(float x) { return x > 0.f ? x : SLOPE * x; }

// Single-pass sorted-descending top-K insert (branchless select chain).
// Strict > keeps earlier indices on ties (matches jax.lax.top_k lower-index-first).
__device__ __forceinline__ void topk_insert(float (&bd)[K_NN], int (&bi)[K_NN], float nd, int ji) {
  bool c[K_NN];
#pragma unroll
  for (int j = 0; j < K_NN; ++j) c[j] = nd > bd[j];
#pragma unroll
  for (int j = K_NN - 1; j >= 1; --j) {
    bd[j] = c[j] ? (c[j - 1] ? bd[j - 1] : nd) : bd[j];
    bi[j] = c[j] ? (c[j - 1] ? bi[j - 1] : ji) : bi[j];
  }
  bd[0] = c[0] ? nd : bd[0];
  bi[0] = c[0] ? ji : bi[0];
}

// ---------------------------------------------------------------- x0 / coords / masks
__global__ void build_x0_coords(const float* __restrict__ coords, const float* __restrict__ feats,
                                float* __restrict__ x0, float* __restrict__ oC,
                                float* __restrict__ oM, int N) {
  int n = blockIdx.x * 256 + threadIdx.x;
  if (n >= N) return;
  float c0 = coords[n * 3 + 0], c1 = coords[n * 3 + 1], c2 = coords[n * 3 + 2];
  float f = feats[n];
  float4 v = make_float4(c0, c1, c2, f);
  *(float4*)(x0 + (size_t)n * 4) = v;
#pragma unroll
  for (int s = 0; s < 3; ++s) {
    size_t b = (size_t)s * N * 3 + (size_t)n * 3;
    oC[b + 0] = c0; oC[b + 1] = c1; oC[b + 2] = c2;
    oM[(size_t)s * N + n] = 0.f;
  }
}

// ---------------------------------------------------------------- squared norms (fp32, exact)
__global__ void compute_xx(const float* __restrict__ x, int ld, int C,
                           float* __restrict__ xx, int N) {
  int n = blockIdx.x * 256 + threadIdx.x;
  if (n >= N) return;
  const float* r = x + (size_t)n * ld;
  float s = 0.f;
  for (int c = 0; c < C; c += 4) {
    float4 v = *(const float4*)(r + c);
    s += v.x * v.x; s += v.y * v.y; s += v.z * v.z; s += v.w * v.w;
  }
  xx[n] = s;
}

// ---------------------------------------------------------------- fp16 hi/lo split prep
template <int C>
__global__ void prep_hl(const float* __restrict__ x, int ld, _Float16* __restrict__ xh,
                        _Float16* __restrict__ xl, int N) {
  constexpr int C4 = C / 4;
  int i = blockIdx.x * 256 + threadIdx.x;  // over N*C/4
  if (i >= N * C4) return;
  int n = i / C4, c4 = i % C4;  // C4 pow2 -> cheap
  float4 v = *(const float4*)(x + (size_t)n * ld + c4 * 4);
  h4 hh, ll;
  hh[0] = (_Float16)v.x; ll[0] = (_Float16)(v.x - (float)hh[0]);
  hh[1] = (_Float16)v.y; ll[1] = (_Float16)(v.y - (float)hh[1]);
  hh[2] = (_Float16)v.z; ll[2] = (_Float16)(v.z - (float)hh[2]);
  hh[3] = (_Float16)v.w; ll[3] = (_Float16)(v.w - (float)hh[3]);
  *(h4*)(xh + (size_t)n * C + c4 * 4) = hh;
  *(h4*)(xl + (size_t)n * C + c4 * 4) = ll;
}

// ---------------------------------------------------------------- small-C fused kNN (layer 1 only)
template <int C>
__global__ __launch_bounds__(256, 2) void knn_seg(
    const float* __restrict__ xP, int ld, const float* __restrict__ xx,
    float* __restrict__ pd, int* __restrict__ pi, int N, int segLen) {
  constexpr int T = 64;
  __shared__ float tile[T * C];
  __shared__ float txx[T];
  __shared__ float sd_st[SCAP * 256];
  __shared__ int si_st[SCAP * 256];
  int tid = threadIdx.x;
  int q = blockIdx.x * 256 + tid;
  int j0 = blockIdx.y * segLen;

  float4 qv[C / 4];
#pragma unroll
  for (int c4 = 0; c4 < C / 4; ++c4) qv[c4] = *(const float4*)(xP + (size_t)q * ld + c4 * 4);
  float xxq = xx[q];

  float bd[K_NN]; int bi[K_NN];
#pragma unroll
  for (int k = 0; k < K_NN; ++k) { bd[k] = -INFINITY; bi[k] = 0; }
  float thr = -INFINITY;
  int cnt = 0;

  for (int jt = j0; jt < j0 + segLen; jt += T) {
    constexpr int TOT4 = T * C / 4;
    for (int f = tid; f < TOT4; f += 256) {
      int t = f / (C / 4), c4 = f % (C / 4);
      *(float4*)(tile + t * C + c4 * 4) = *(const float4*)(xP + (size_t)(jt + t) * ld + c4 * 4);
    }
    if (tid < T) txx[tid] = xx[jt + tid];
    __syncthreads();
#pragma unroll 2
    for (int t = 0; t < T; ++t) {
      const float4* rp = (const float4*)(tile + t * C);
      float dot = 0.f;
#pragma unroll
      for (int c4 = 0; c4 < C / 4; ++c4) {
        float4 v = rp[c4];
        dot += qv[c4].x * v.x; dot += qv[c4].y * v.y;
        dot += qv[c4].z * v.z; dot += qv[c4].w * v.w;
      }
      float nd = 2.f * dot - xxq - txx[t];
      if (nd > thr) {
        sd_st[cnt * 256 + tid] = nd;
        si_st[cnt * 256 + tid] = jt + t;
        cnt++;
      }
      if (__any(cnt == SCAP)) {
        for (int e = 0; e < cnt; ++e) {
          float dnd = sd_st[e * 256 + tid];
          int dji = si_st[e * 256 + tid];
          if (dnd > bd[K_NN - 1]) topk_insert(bd, bi, dnd, dji);
        }
        cnt = 0;
        thr = bd[K_NN - 1];
      }
    }
    __syncthreads();
  }
  for (int e = 0; e < cnt; ++e) {
    float dnd = sd_st[e * 256 + tid];
    int dji = si_st[e * 256 + tid];
    if (dnd > bd[K_NN - 1]) topk_insert(bd, bi, dnd, dji);
  }

  size_t base = ((size_t)blockIdx.y * N + q) * K_NN;
#pragma unroll
  for (int k = 0; k < K_NN; ++k) { pd[base + k] = bd[k]; pi[base + k] = bi[k]; }
}

// ---------------------------------------------------------------- merge per-segment top-k lists (layer 1)
__global__ void knn_merge(const float* __restrict__ pd, const int* __restrict__ pi,
                          int* __restrict__ idx, int N, int S) {
  int q = blockIdx.x * 256 + threadIdx.x;
  if (q >= N) return;
  float bd[K_NN]; int bi[K_NN];
#pragma unroll
  for (int k = 0; k < K_NN; ++k) { bd[k] = -INFINITY; bi[k] = 0; }
  for (int s = 0; s < S; ++s) {
    size_t base = ((size_t)s * N + q) * K_NN;
    for (int k = 0; k < K_NN; ++k) {
      float nd = pd[base + k];
      if (!(nd > bd[K_NN - 1])) break;
      topk_insert(bd, bi, nd, pi[base + k]);
    }
  }
#pragma unroll
  for (int k = 0; k < K_NN; ++k) idx[(size_t)q * K_NN + k] = bi[k];
}

// ---------------------------------------------------------------- MFMA kNN (C = 64 / 128)
// D[cand][query] = mfma(A=cand hi/lo, B=query hi/lo): 3 passes (hh, hl, lh).
// Lane owns query=lane&15, 4 cands per acc reg -> per-lane register top-k.
// 8 waves = 4 query-groups x 2 candidate-halves; dbuf XOR-swizzled LDS cand tiles;
// deferred LDS-stack inserts; final 8-list merge with index tie-break.
template <int C>
__global__ __launch_bounds__(512, 2) void knn_mfma(
    const _Float16* __restrict__ xh, const _Float16* __restrict__ xl,
    const float* __restrict__ xx, int* __restrict__ idx, int N) {
  constexpr int SLOTS = C / 8;        // 16B units per row
  constexpr int SWM = SLOTS - 1;
  constexpr int NCH = C / 32;         // K-chunks per pass (4 or 2)
  constexpr int TILE_UNITS = 2 * 32 * SLOTS;  // hi+lo, 32 cands, 16B units
  constexpr int UPT = TILE_UNITS / 256;       // staged units per thread
  constexpr int STAGE_B = 2 * 2 * TILE_UNITS * 16;  // 2 ch x 2 buf
  constexpr int MERGE_B = 64 * 8 * K_NN * 8;        // 80 KB
  constexpr int LDS_B = (STAGE_B + 32768 > MERGE_B) ? STAGE_B + 32768 : MERGE_B;
  __shared__ char lds[LDS_B];
  float* sd_st = (float*)(lds + STAGE_B);
  int* si_st = (int*)(lds + STAGE_B + 16384);

  int tid = threadIdx.x;
  int wv = tid >> 6, lane = tid & 63;
  int qh = wv >> 1, ch = wv & 1;
  int lj = lane & 15, g = lane >> 4;
  int q0 = blockIdx.x * 64;
  int q = q0 + qh * 16 + lj;
  int chbase = ch * (N / 2);
  const int NT = (N / 2) / 32;

  // B-frags (queries), loaded once
  h8 bh[NCH], bl[NCH];
#pragma unroll
  for (int m = 0; m < NCH; ++m) {
    bh[m] = *(const h8*)(xh + (size_t)q * C + m * 32 + g * 8);
    bl[m] = *(const h8*)(xl + (size_t)q * C + m * 32 + g * 8);
  }
  float qxx = xx[q];

  float bd[K_NN]; int bi[K_NN];
#pragma unroll
  for (int k = 0; k < K_NN; ++k) { bd[k] = -INFINITY; bi[k] = 0; }
  float thr = -INFINITY;
  int cnt = 0;

  int cidx = qh * 64 + lane;  // 0..255 within this ch-group
  float4 ldr[UPT];

  auto ldreg = [&](int t) {
    int jt = chbase + t * 32;
#pragma unroll
    for (int u = 0; u < UPT; ++u) {
      int p = cidx * UPT + u;
      int part = p / (32 * SLOTS);
      int row = (p / SLOTS) & 31;
      int slot = p & SWM;
      const _Float16* src = part ? xl : xh;
      ldr[u] = *(const float4*)(src + (size_t)(jt + row) * C + (slot ^ (row & SWM)) * 8);
    }
  };
  auto dswrite = [&](int buf) {
#pragma unroll
    for (int u = 0; u < UPT; ++u) {
      int p = cidx * UPT + u;
      *(float4*)(lds + ((size_t)(ch * 2 + buf) * TILE_UNITS + p) * 16) = ldr[u];
    }
  };
  auto compute = [&](int buf, int jt) {
    float cxx[8];
#pragma unroll
    for (int s = 0; s < 2; ++s)
#pragma unroll
      for (int r = 0; r < 4; ++r) cxx[s * 4 + r] = xx[jt + s * 16 + g * 4 + r];
    char* tb = lds + (size_t)(ch * 2 + buf) * TILE_UNITS * 16;
#pragma unroll
    for (int sub = 0; sub < 2; ++sub) {
      int row = sub * 16 + lj;
      h8 ah[NCH], al[NCH];
#pragma unroll
      for (int m = 0; m < NCH; ++m) {
        int su = (m * 4 + g) ^ (row & SWM);
        ah[m] = *(const h8*)(tb + ((size_t)(0 * 32 + row) * SLOTS + su) * 16);
        al[m] = *(const h8*)(tb + ((size_t)(1 * 32 + row) * SLOTS + su) * 16);
      }
      f4v acc = {0.f, 0.f, 0.f, 0.f};
#pragma unroll
      for (int m = 0; m < NCH; ++m)
        acc = __builtin_amdgcn_mfma_f32_16x16x32_f16(ah[m], bh[m], acc, 0, 0, 0);
#pragma unroll
      for (int m = 0; m < NCH; ++m)
        acc = __builtin_amdgcn_mfma_f32_16x16x32_f16(ah[m], bl[m], acc, 0, 0, 0);
#pragma unroll
      for (int m = 0; m < NCH; ++m)
        acc = __builtin_amdgcn_mfma_f32_16x16x32_f16(al[m], bh[m], acc, 0, 0, 0);
#pragma unroll
      for (int r = 0; r < 4; ++r) {
        float d = 2.f * acc[r] - qxx - cxx[sub * 4 + r];
        if (d > thr) {
          sd_st[cnt * 512 + tid] = d;
          si_st[cnt * 512 + tid] = jt + sub * 16 + g * 4 + r;
          cnt++;
        }
        if (__any(cnt == SCAP)) {
          for (int e = 0; e < cnt; ++e) {
            float dnd = sd_st[e * 512 + tid];
            int dji = si_st[e * 512 + tid];
            if (dnd > bd[K_NN - 1]) topk_insert(bd, bi, dnd, dji);
          }
          cnt = 0;
          thr = bd[K_NN - 1];
        }
      }
    }
  };

  ldreg(0);
  dswrite(0);
  __syncthreads();
  for (int t = 0; t < NT; ++t) {
    int cur = t & 1;
    if (t + 1 < NT) ldreg(t + 1);
    compute(cur, chbase + t * 32);
    __syncthreads();
    if (t + 1 < NT) {
      dswrite(cur ^ 1);
      __syncthreads();
    }
  }
  // final drain
  for (int e = 0; e < cnt; ++e) {
    float dnd = sd_st[e * 512 + tid];
    int dji = si_st[e * 512 + tid];
    if (dnd > bd[K_NN - 1]) topk_insert(bd, bi, dnd, dji);
  }
  __syncthreads();  // stage+stack dead; merge overlay begins

  float* mg = (float*)lds;
  int list = ch * 4 + g;
  int qlocal = qh * 16 + lj;
#pragma unroll
  for (int k = 0; k < K_NN; ++k) {
    int e = ((qlocal * 8 + list) * K_NN + k) * 2;
    mg[e] = bd[k];
    ((int*)mg)[e + 1] = bi[k];
  }
  __syncthreads();
  if (tid < 64) {  // wave 0 merges all 64 queries (8 sorted lists each)
    int pr[8] = {0, 0, 0, 0, 0, 0, 0, 0};
    float hd[8]; int hx[8];
#pragma unroll
    for (int j = 0; j < 8; ++j) {
      int e = ((tid * 8 + j) * K_NN) * 2;
      hd[j] = mg[e]; hx[j] = ((int*)mg)[e + 1];
    }
    for (int k = 0; k < K_NN; ++k) {
      float best = hd[0]; int bidx = hx[0]; int bj = 0;
#pragma unroll
      for (int j = 1; j < 8; ++j) {
        bool btr = (hd[j] > best) || (hd[j] == best && hx[j] < bidx);
        best = btr ? hd[j] : best;
        bidx = btr ? hx[j] : bidx;
        bj = btr ? j : bj;
      }
      idx[(size_t)(q0 + tid) * K_NN + k] = bidx;
#pragma unroll
      for (int j = 0; j < 8; ++j) {
        if (j == bj) {
          pr[j]++;
          if (pr[j] < K_NN) {
            int e = ((tid * 8 + j) * K_NN + pr[j]) * 2;
            hd[j] = mg[e]; hx[j] = ((int*)mg)[e + 1];
          } else {
            hd[j] = -INFINITY; hx[j] = 0x7fffffff;
          }
        }
      }
    }
  }
}

// ---------------------------------------------------------------- weight prep: wcat = [w_A ; w_B - w_A]
__global__ void prep_wcat(const float* __restrict__ w, float* __restrict__ wcat, int O, int C) {
  int i = blockIdx.x * 256 + threadIdx.x;
  if (i >= O * C) return;
  int o = i / C, c = i % C;
  float wa = w[(size_t)o * 2 * C + c];
  float wb = w[(size_t)o * 2 * C + C + c];
  wcat[(size_t)o * C + c] = wa;
  wcat[((size_t)O + o) * C + c] = wb - wa;
}

// ---------------------------------------------------------------- tiled SGEMM-NT: Out[m][n] = ep(sum_k A[m][k]*B[n][k])
template <int MODE>
__global__ __launch_bounds__(256) void gemm_nt(
    const float* __restrict__ A, int lda, const float* __restrict__ B, int ldb,
    float* __restrict__ Out, int ldo, int M, int Nout, int Kdim,
    const float* __restrict__ sv, const float* __restrict__ cv) {
  __shared__ float As[TK][64];
  __shared__ float Bs[TK][64];
  int tid = threadIdx.x;
  int tx = tid & 15, ty = tid >> 4;
  int m0 = blockIdx.x * 64, n0 = blockIdx.y * 64;
  int lrow = tid >> 2, lkq = tid & 3;
  float acc[4][4] = {};

  for (int k0 = 0; k0 < Kdim; k0 += TK) {
    float4 av = make_float4(0.f, 0.f, 0.f, 0.f), bv = make_float4(0.f, 0.f, 0.f, 0.f);
    if (k0 + lkq * 4 < Kdim) {
      av = *(const float4*)(A + (size_t)(m0 + lrow) * lda + k0 + lkq * 4);
      bv = *(const float4*)(B + (size_t)(n0 + lrow) * ldb + k0 + lkq * 4);
    }
    As[lkq * 4 + 0][lrow] = av.x; As[lkq * 4 + 1][lrow] = av.y;
    As[lkq * 4 + 2][lrow] = av.z; As[lkq * 4 + 3][lrow] = av.w;
    Bs[lkq * 4 + 0][lrow] = bv.x; Bs[lkq * 4 + 1][lrow] = bv.y;
    Bs[lkq * 4 + 2][lrow] = bv.z; Bs[lkq * 4 + 3][lrow] = bv.w;
    __syncthreads();
#pragma unroll
    for (int kk = 0; kk < TK; ++kk) {
      float a[4], b[4];
      *(float4*)a = *(const float4*)&As[kk][ty * 4];
      *(float4*)b = *(const float4*)&Bs[kk][tx * 4];
#pragma unroll
      for (int i = 0; i < 4; ++i)
#pragma unroll
        for (int j = 0; j < 4; ++j) acc[i][j] += a[i] * b[j];
    }
    __syncthreads();
  }

  float4 s4 = make_float4(1.f, 1.f, 1.f, 1.f), c4 = make_float4(0.f, 0.f, 0.f, 0.f);
  if (MODE != 0) {
    s4 = *(const float4*)(sv + n0 + tx * 4);
    c4 = *(const float4*)(cv + n0 + tx * 4);
  }
#pragma unroll
  for (int i = 0; i < 4; ++i) {
    float4 r = make_float4(acc[i][0], acc[i][1], acc[i][2], acc[i][3]);
    if (MODE != 0) {
      r.x = r.x * s4.x + c4.x; r.y = r.y * s4.y + c4.y;
      r.z = r.z * s4.z + c4.z; r.w = r.w * s4.w + c4.w;
    }
    if (MODE == 1) { r.x = lrelu(r.x); r.y = lrelu(r.y); r.z = lrelu(r.z); r.w = lrelu(r.w); }
    *(float4*)(Out + (size_t)(m0 + ty * 4 + i) * ldo + n0 + tx * 4) = r;
  }
}

// ---------------------------------------------------------------- gather-max epilogue of EdgeConv
template <int O>
__global__ void edge_max(const float* __restrict__ U, const int* __restrict__ idx,
                         const float* __restrict__ sv, const float* __restrict__ cv,
                         float* __restrict__ out, int N) {
  constexpr int TPP = O / 4;
  constexpr int PPB = 256 / TPP;
  int tid = threadIdx.x;
  int n = blockIdx.x * PPB + tid / TPP;
  int o4 = tid % TPP;
  const int* ir = idx + (size_t)n * K_NN;
  float4 m = make_float4(-INFINITY, -INFINITY, -INFINITY, -INFINITY);
#pragma unroll
  for (int k = 0; k < K_NN; ++k) {
    int j = ir[k];
    float4 t = *(const float4*)(U + (size_t)j * (2 * O) + o4 * 4);
    m.x = fmaxf(m.x, t.x); m.y = fmaxf(m.y, t.y);
    m.z = fmaxf(m.z, t.z); m.w = fmaxf(m.w, t.w);
  }
  float4 v = *(const float4*)(U + (size_t)n * (2 * O) + O + o4 * 4);
  float4 s4 = *(const float4*)(sv + o4 * 4);
  float4 c4 = *(const float4*)(cv + o4 * 4);
  float4 r;
  r.x = lrelu(s4.x * (v.x + m.x) + c4.x);
  r.y = lrelu(s4.y * (v.y + m.y) + c4.y);
  r.z = lrelu(s4.z * (v.z + m.z) + c4.z);
  r.w = lrelu(s4.w * (v.w + m.w) + c4.w);
  *(float4*)(out + (size_t)n * 512 + o4 * 4) = r;
}

// ---------------------------------------------------------------- transpose (N,768) -> (768,N)
__global__ void transpose_nt(const float* __restrict__ in, float* __restrict__ out, int N, int Cc) {
  __shared__ float t[32][33];
  int bx = blockIdx.x, by = blockIdx.y;
  int lx = threadIdx.x, ly = threadIdx.y;
#pragma unroll
  for (int i = 0; i < 4; ++i)
    t[ly + i * 8][lx] = in[(size_t)(by * 32 + ly + i * 8) * Cc + bx * 32 + lx];
  __syncthreads();
#pragma unroll
  for (int i = 0; i < 4; ++i)
    out[(size_t)(bx * 32 + ly + i * 8) * N + by * 32 + lx] = t[lx][ly + i * 8];
}

// ---------------------------------------------------------------- sem logits
__global__ void sem_kernel(const float* __restrict__ T1, const float* __restrict__ wsem,
                           const float* __restrict__ bsem, float* __restrict__ out, int N) {
  int tid = threadIdx.x;
  int n = blockIdx.x * 8 + (tid >> 5);
  int g = tid & 31;
  if (g < 20) {
    const float* row = T1 + (size_t)n * 768 + 512;
    const float* wr = wsem + (size_t)g * 256;
    float acc = 0.f;
    for (int o = 0; o < 256; ++o) acc += row[o] * wr[o];
    out[(size_t)n * 20 + g] = acc + bsem[g];
  }
}

// ---------------------------------------------------------------- per-layer drivers
template <int C, int O>
static void run_layer_seg(const float* x, int ld, const float* wc, const float* sv,
                          const float* cv, float* outcol, float* xxb, int* idxb, float* pd,
                          int* pi, float* U, int N, hipStream_t stream) {
  compute_xx<<<N / 256, 256, 0, stream>>>(x, ld, C, xxb, N);
  knn_seg<C><<<dim3(N / 256, NSEG), 256, 0, stream>>>(x, ld, xxb, pd, pi, N, N / NSEG);
  knn_merge<<<N / 256, 256, 0, stream>>>(pd, pi, idxb, N, NSEG);
  gemm_nt<0><<<dim3(N / 64, (2 * O) / 64), 256, 0, stream>>>(x, ld, wc, C, U, 2 * O, N, 2 * O, C,
                                                             nullptr, nullptr);
  edge_max<O><<<N / (256 / (O / 4)), 256, 0, stream>>>(U, idxb, sv, cv, outcol, N);
}

template <int C, int O>
static void run_layer_mfma(const float* x, int ld, const float* wc, const float* sv,
                           const float* cv, float* outcol, float* xxb, int* idxb,
                           _Float16* xh, _Float16* xl, float* U, int N, hipStream_t stream) {
  compute_xx<<<N / 256, 256, 0, stream>>>(x, ld, C, xxb, N);
  prep_hl<C><<<(N * (C / 4)) / 256, 256, 0, stream>>>(x, ld, xh, xl, N);
  knn_mfma<C><<<N / 64, 512, 0, stream>>>(xh, xl, xxb, idxb, N);
  gemm_nt<0><<<dim3(N / 64, (2 * O) / 64), 256, 0, stream>>>(x, ld, wc, C, U, 2 * O, N, 2 * O, C,
                                                             nullptr, nullptr);
  edge_max<O><<<N / (256 / (O / 4)), 256, 0, stream>>>(U, idxb, sv, cv, outcol, N);
}

extern "C" void kernel_launch(void* const* d_in, const int* in_sizes, int n_in,
                              void* d_out, int out_size, void* d_ws, size_t ws_size,
                              hipStream_t stream) {
  const int N = in_sizes[0] / 3;  // 16384
  const float* coords = (const float*)d_in[0];
  const float* feats  = (const float*)d_in[1];
  const float* w1 = (const float*)d_in[2];
  const float* s1 = (const float*)d_in[3];
  const float* c1 = (const float*)d_in[4];
  const float* w2 = (const float*)d_in[5];
  const float* s2 = (const float*)d_in[6];
  const float* c2 = (const float*)d_in[7];
  const float* w3 = (const float*)d_in[8];
  const float* s3 = (const float*)d_in[9];
  const float* c3 = (const float*)d_in[10];
  const float* w4 = (const float*)d_in[11];
  const float* s4 = (const float*)d_in[12];
  const float* c4 = (const float*)d_in[13];
  const float* w5 = (const float*)d_in[14];
  const float* s5 = (const float*)d_in[15];
  const float* c5 = (const float*)d_in[16];
  const float* wf = (const float*)d_in[17];
  const float* sf = (const float*)d_in[18];
  const float* cf = (const float*)d_in[19];
  const float* wsem = (const float*)d_in[20];
  const float* bsem = (const float*)d_in[21];

  // workspace layout (floats). pd/pi alias T1; xh/xl alias UX5 (both dead when owner live).
  float* base = (float*)d_ws;
  size_t off = 0;
  float* XC  = base + off; off += (size_t)N * 512;   // [x1|x2|x3|x4] point-major, stride 512
  float* UX5 = base + off; off += (size_t)N * 512;   // u|v tables / x5; kNN hi-lo aliases
  float* x0  = base + off; off += (size_t)N * 4;
  float* xxb = base + off; off += (size_t)N;
  int*   idxb = (int*)(base + off); off += (size_t)N * K_NN;
  float* wc1 = base + off; off += 128 * 4;
  float* wc2 = base + off; off += 128 * 64;
  float* wc3 = base + off; off += 256 * 64;
  float* wc4 = base + off; off += 512 * 128;
  float* T1  = base + off; off += (size_t)N * 768;
  float* pd = T1;
  int*   pi = (int*)(T1 + (size_t)NSEG * N * K_NN);
  _Float16* xh = (_Float16*)UX5;                 // up to N*128 f16 = 4MB
  _Float16* xl = (_Float16*)(UX5 + (size_t)N * 64);

  float* oF = (float*)d_out;                       // ms_feats (3,256,N)
  float* oC = oF + (size_t)3 * 256 * N;            // ms_coords (3,N,3)
  float* oM = oC + (size_t)3 * N * 3;              // ms_masks (3,N)
  float* oL = oM + (size_t)3 * N;                  // sem_logits (1,N,20)

  build_x0_coords<<<N / 256, 256, 0, stream>>>(coords, feats, x0, oC, oM, N);

  prep_wcat<<<(64 * 4 + 255) / 256, 256, 0, stream>>>(w1, wc1, 64, 4);
  prep_wcat<<<(64 * 64 + 255) / 256, 256, 0, stream>>>(w2, wc2, 64, 64);
  prep_wcat<<<(128 * 64 + 255) / 256, 256, 0, stream>>>(w3, wc3, 128, 64);
  prep_wcat<<<(256 * 128 + 255) / 256, 256, 0, stream>>>(w4, wc4, 256, 128);

  run_layer_seg<4, 64>(x0, 4, wc1, s1, c1, XC + 0, xxb, idxb, pd, pi, UX5, N, stream);
  run_layer_mfma<64, 64>(XC + 0, 512, wc2, s2, c2, XC + 64, xxb, idxb, xh, xl, UX5, N, stream);
  run_layer_mfma<64, 128>(XC + 64, 512, wc3, s3, c3, XC + 128, xxb, idxb, xh, xl, UX5, N, stream);
  run_layer_mfma<128, 256>(XC + 128, 512, wc4, s4, c4, XC + 256, xxb, idxb, xh, xl, UX5, N, stream);

  // x5 = lrelu(w5 @ cat * s5 + c5)  -> UX5 (N,512)
  gemm_nt<1><<<dim3(N / 64, 8), 256, 0, stream>>>(XC, 512, w5, 512, UX5, 512, N, 512, 512, s5, c5);
  // T1 = x5 @ wf^T * sf + cf  (wf viewed as (768,512))  -> (N,768)
  gemm_nt<2><<<dim3(N / 64, 12), 256, 0, stream>>>(UX5, 512, wf, 512, T1, 768, N, 768, 512, sf, cf);
  // ms_feats = T1^T
  transpose_nt<<<dim3(24, N / 32), dim3(32, 8), 0, stream>>>(T1, oF, N, 768);
  // sem_logits from T1 cols [512,768)
  sem_kernel<<<N / 8, 256, 0, stream>>>(T1, wsem, bsem, oL, N);
}